// Round 1
// baseline (141.068 us; speedup 1.0000x reference)
//
#include <hip/hip_runtime.h>
#include <math.h>

#define BN 8192
#define NT 256
#define INV_TAU (1.0f / 0.07f)
#define NEGF (-1e30f)

struct WsLayout {
  double bins_pu[64];   // per-row PU losses, binned
  double bins_ir[64];   // infonce row part: sum(logZ_full_row - diag)
  double bins_ic[64];   // infonce col part
  double acc_prior;     // sum (pi_a - pi_ext)^2
  float w_inf, w_pu, w_prior;
  int P_tot, RN_tot, U_tot;
  float A_tot;          // sum of alphas over label==1
};

__device__ __forceinline__ void merge_lse(float& m, float& se, float& sp, float& srn, float& su,
                                          float m2, float se2, float sp2, float srn2, float su2) {
  float mn = fmaxf(m, m2);
  float c1 = __expf(m - mn);
  float c2 = __expf(m2 - mn);
  se  = se  * c1 + se2  * c2;
  sp  = sp  * c1 + sp2  * c2;
  srn = srn * c1 + srn2 * c2;
  su  = su  * c1 + su2  * c2;
  m = mn;
}

// ---------------- init: zero accumulators, label stats, curriculum weights ----------------
__global__ void init_kernel(const int* __restrict__ labels, const float* __restrict__ alphas,
                            const int* __restrict__ epoch_p, WsLayout* __restrict__ ws) {
  __shared__ int sP[NT], sRN[NT], sU[NT];
  __shared__ float sA[NT];
  int t = threadIdx.x;
  int p = 0, rn = 0, u = 0;
  float a = 0.f;
  for (int j = t; j < BN; j += NT) {
    int l = labels[j];
    p  += (l == 1);
    rn += (l == -1);
    u  += (l == 0);
    if (l == 1) a += alphas[j];
  }
  sP[t] = p; sRN[t] = rn; sU[t] = u; sA[t] = a;
  __syncthreads();
  for (int s = NT / 2; s > 0; s >>= 1) {
    if (t < s) { sP[t] += sP[t + s]; sRN[t] += sRN[t + s]; sU[t] += sU[t + s]; sA[t] += sA[t + s]; }
    __syncthreads();
  }
  if (t < 64) {
    ws->bins_pu[t] = 0.0;
    ws->bins_ir[t] = 0.0;
    ws->bins_ic[t] = 0.0;
  }
  if (t == 0) {
    ws->acc_prior = 0.0;
    ws->P_tot = sP[0]; ws->RN_tot = sRN[0]; ws->U_tot = sU[0]; ws->A_tot = sA[0];
    int ep = epoch_p[0];
    float w_inf, w_pu, w_prior;
    if (ep < 5) { w_inf = 1.f; w_pu = 0.f; w_prior = 0.f; }
    else {
      float puw = (ep >= 15) ? 1.f : (float)(ep - 5) / 10.f;
      w_inf = 1.f - puw; w_pu = puw; w_prior = (ep >= 15) ? 1.f : 0.f;
    }
    ws->w_inf = w_inf; ws->w_pu = w_pu; ws->w_prior = w_prior;
  }
}

// ---------------- per-row PU loss (+ gated infonce row LSE) ----------------
__launch_bounds__(NT)
__global__ void row_kernel(const float* __restrict__ sim, const float* __restrict__ pw,
                           const int* __restrict__ labels, const float* __restrict__ alphas,
                           const float* __restrict__ betas, const float* __restrict__ pia,
                           WsLayout* __restrict__ ws) {
  const int row = blockIdx.x;
  const bool do_pu  = (ws->w_pu  != 0.0f);
  const bool do_inf = (ws->w_inf != 0.0f);
  if (!do_pu && !do_inf) return;

  const float4* sim4 = (const float4*)(sim + (size_t)row * BN);
  const float4* pw4  = (const float4*)(pw  + (size_t)row * BN);
  const int4*   lb4  = (const int4*)labels;
  const float4* al4  = (const float4*)alphas;
  const float4* be4  = (const float4*)betas;

  float m = NEGF, se = 0.f, sp = 0.f, srn = 0.f, su = 0.f;
  float salpha = 0.f, diag = 0.f;

  for (int v = threadIdx.x; v < BN / 4; v += NT) {
    float4 s4 = sim4[v];
    int4   l4 = lb4[v];
    float4 a4 = al4[v];
    float4 b4 = be4[v];
    float4 w4;
    if (do_pu) w4 = pw4[v]; else { w4.x = w4.y = w4.z = w4.w = 0.f; }
    const int jb = 4 * v;
    float sv[4] = {s4.x, s4.y, s4.z, s4.w};
    float wv[4] = {w4.x, w4.y, w4.z, w4.w};
    int   lv[4] = {l4.x, l4.y, l4.z, l4.w};
    float av[4] = {a4.x, a4.y, a4.z, a4.w};
    float bv[4] = {b4.x, b4.y, b4.z, b4.w};
#pragma unroll
    for (int c = 0; c < 4; ++c) {
      const int j = jb + c;
      const float l = sv[c] * INV_TAU;
      const bool self = (j == row);
      if (self) diag = l;
      const float lval = self ? NEGF : l;       // mirror reference's NEG masking
      if (lval > m) {                            // rare online-softmax rescale
        const float sc = __expf(m - lval);
        se *= sc; sp *= sc; srn *= sc; su *= sc;
        m = lval;
      }
      const float ex = __expf(lval - m);         // 0 for self (underflow)
      se += ex;
      const bool isp = (lv[c] == 1);
      sp += isp ? ex : 0.f;
      salpha = fmaf((isp && !self) ? av[c] : 0.f, l, salpha);
      srn = fmaf((lv[c] == -1) ? bv[c] * wv[c] : 0.f, ex, srn);
      su  = fmaf((lv[c] ==  0) ? wv[c] : 0.f, ex, su);
    }
  }

  // wave (64-lane) butterfly reduce
#pragma unroll
  for (int off = 32; off > 0; off >>= 1) {
    float m2   = __shfl_xor(m, off);
    float se2  = __shfl_xor(se, off);
    float sp2  = __shfl_xor(sp, off);
    float srn2 = __shfl_xor(srn, off);
    float su2  = __shfl_xor(su, off);
    salpha += __shfl_xor(salpha, off);
    diag   += __shfl_xor(diag, off);
    merge_lse(m, se, sp, srn, su, m2, se2, sp2, srn2, su2);
  }

  __shared__ float red[4][7];
  const int wid  = threadIdx.x >> 6;
  const int lane = threadIdx.x & 63;
  if (lane == 0) {
    red[wid][0] = m;  red[wid][1] = se;     red[wid][2] = sp; red[wid][3] = srn;
    red[wid][4] = su; red[wid][5] = salpha; red[wid][6] = diag;
  }
  __syncthreads();
  if (threadIdx.x == 0) {
    float M = red[0][0], Se = red[0][1], Sp = red[0][2], Sr = red[0][3], Su = red[0][4];
    float Sa = red[0][5], Dg = red[0][6];
    for (int w = 1; w < 4; ++w) {
      merge_lse(M, Se, Sp, Sr, Su, red[w][0], red[w][1], red[w][2], red[w][3], red[w][4]);
      Sa += red[w][5];
      Dg += red[w][6];
    }
    const double logZ = (double)M + log((double)Se);
    if (do_pu) {
      const int li  = labels[row];
      const int cp  = ws->P_tot  - (li == 1 ? 1 : 0);
      const int crn = ws->RN_tot - (li == -1 ? 1 : 0);
      const int cu  = ws->U_tot  - (li == 0 ? 1 : 0);
      const double Apos = (double)ws->A_tot - (li == 1 ? (double)alphas[row] : 0.0);
      const double Lpos = (cp > 0) ? (-((double)Sa - logZ * Apos) / cp) : 0.0;
      const double Lrn  = (crn > 0) ? (((double)Sr / (double)Se) / crn) : 0.0;
      const double EU = ((double)Su / (double)Se) / (cu > 0 ? cu : 1);
      const double EP = ((double)Sp / (double)Se) / (cp > 0 ? cp : 1);
      double pi = (double)pia[row];
      pi = pi < 1e-4 ? 1e-4 : (pi > 0.5 ? 0.5 : pi);
      const double deb = (EU - pi * EP) / (1.0 - pi + 1e-8);
      const double Lu = (cu > 0 && cp > 0) ? (deb > 0.0 ? deb : 0.0) : 0.0;
      atomicAdd(&ws->bins_pu[row & 63], Lpos + Lrn + Lu);
    }
    if (do_inf) {
      // full-row logsumexp includes the diagonal
      const double dM = fmax((double)M, (double)Dg);
      const double sf = (double)Se * exp((double)M - dM) + exp((double)Dg - dM);
      const double logZf = dM + log(sf);
      atomicAdd(&ws->bins_ir[row & 63], logZf - (double)Dg);
    }
  }
}

// ---------------- infonce column LSE (only runs when epoch < PHASE2_END) ----------------
__launch_bounds__(NT)
__global__ void col_kernel(const float* __restrict__ sim, WsLayout* __restrict__ ws) {
  if (ws->w_inf == 0.0f) return;
  const int col = blockIdx.x;
  float m = NEGF, se = 0.f, diag = 0.f;
  for (int r = threadIdx.x; r < BN; r += NT) {
    float l = sim[(size_t)r * BN + col] * INV_TAU;
    if (r == col) diag = l;
    if (l > m) { se *= __expf(m - l); m = l; }
    se += __expf(l - m);
  }
#pragma unroll
  for (int off = 32; off > 0; off >>= 1) {
    float m2 = __shfl_xor(m, off), se2 = __shfl_xor(se, off);
    diag += __shfl_xor(diag, off);
    float mn = fmaxf(m, m2);
    se = se * __expf(m - mn) + se2 * __expf(m2 - mn);
    m = mn;
  }
  __shared__ float red[4][3];
  const int wid = threadIdx.x >> 6;
  const int lane = threadIdx.x & 63;
  if (lane == 0) { red[wid][0] = m; red[wid][1] = se; red[wid][2] = diag; }
  __syncthreads();
  if (threadIdx.x == 0) {
    float M = red[0][0], Se = red[0][1], Dg = red[0][2];
    for (int w = 1; w < 4; ++w) {
      float mn = fmaxf(M, red[w][0]);
      Se = Se * __expf(M - mn) + red[w][1] * __expf(red[w][0] - mn);
      M = mn;
      Dg += red[w][2];
    }
    const double logZf = (double)M + log((double)Se);
    atomicAdd(&ws->bins_ic[col & 63], logZf - (double)Dg);
  }
}

// ---------------- prior term ----------------
__global__ void prior_kernel(const float* __restrict__ pia, const float* __restrict__ pie,
                             WsLayout* __restrict__ ws) {
  __shared__ float sb[NT];
  float a = 0.f;
  for (int j = threadIdx.x; j < BN; j += NT) {
    float d = pia[j] - pie[j];
    a = fmaf(d, d, a);
  }
  sb[threadIdx.x] = a;
  __syncthreads();
  for (int s = NT / 2; s > 0; s >>= 1) {
    if (threadIdx.x < s) sb[threadIdx.x] += sb[threadIdx.x + s];
    __syncthreads();
  }
  if (threadIdx.x == 0) ws->acc_prior = (double)sb[0];
}

// ---------------- final combine ----------------
__global__ void final_kernel(const WsLayout* __restrict__ ws, float* __restrict__ out) {
  int t = threadIdx.x;  // 64 threads
  double pu = ws->bins_pu[t];
  double ir = ws->bins_ir[t];
  double ic = ws->bins_ic[t];
#pragma unroll
  for (int off = 32; off > 0; off >>= 1) {
    pu += __shfl_xor(pu, off);
    ir += __shfl_xor(ir, off);
    ic += __shfl_xor(ic, off);
  }
  if (t == 0) {
    const double loss_pu  = pu / (double)BN;
    const double loss_inf = (ir + ic) / (2.0 * (double)BN);
    const double prior    = ws->acc_prior / (double)BN;
    const double total = (double)ws->w_inf * loss_inf
                       + (double)ws->w_pu * loss_pu
                       + (double)ws->w_prior * 0.1 * prior;
    out[0] = (float)total;
  }
}

extern "C" void kernel_launch(void* const* d_in, const int* in_sizes, int n_in,
                              void* d_out, int out_size, void* d_ws, size_t ws_size,
                              hipStream_t stream) {
  const float* sim    = (const float*)d_in[0];
  const int*   labels = (const int*)d_in[1];
  const float* alphas = (const float*)d_in[2];
  const float* betas  = (const float*)d_in[3];
  const float* pia    = (const float*)d_in[4];
  const float* pw     = (const float*)d_in[5];
  const float* pie    = (const float*)d_in[6];
  const int*   epoch  = (const int*)d_in[7];
  WsLayout* ws = (WsLayout*)d_ws;
  float* out = (float*)d_out;

  hipLaunchKernelGGL(init_kernel, dim3(1), dim3(NT), 0, stream, labels, alphas, epoch, ws);
  hipLaunchKernelGGL(row_kernel, dim3(BN), dim3(NT), 0, stream, sim, pw, labels, alphas, betas, pia, ws);
  hipLaunchKernelGGL(col_kernel, dim3(BN), dim3(NT), 0, stream, sim, ws);
  hipLaunchKernelGGL(prior_kernel, dim3(1), dim3(NT), 0, stream, pia, pie, ws);
  hipLaunchKernelGGL(final_kernel, dim3(1), dim3(64), 0, stream, ws, out);
}

// Round 2
// 133.012 us; speedup vs baseline: 1.0606x; 1.0606x over previous
//
#include <hip/hip_runtime.h>
#include <math.h>

#define BN 8192
#define NT 512
#define NW (NT / 64)
#define INV_TAU (1.0f / 0.07f)

struct WsLayout {
  double bins_pu[64];   // per-row PU losses, binned
  double bins_ir[64];   // infonce row part
  double bins_ic[64];   // infonce col part
  double acc_prior;     // sum (pi_a - pi_ext)^2
  float w_inf, w_pu, w_prior;
  int P_tot, RN_tot, U_tot;
  float A_tot;          // sum of alphas over label==1
};

// ---------------- prep: zero accumulators, label stats, weights, prior, selector arrays ----
// code layout (floats): [0..BN)   asel  = label==1  ? alpha : 0
//                       [BN..2BN) psel  = label==1  ? 1     : 0
//                       [2BN..3BN) rb   = label==-1 ? beta  : 0
//                       [3BN..4BN) usel = label==0  ? 1     : 0
__global__ void prep_kernel(const int* __restrict__ labels, const float* __restrict__ alphas,
                            const float* __restrict__ betas, const float* __restrict__ pia,
                            const float* __restrict__ pie, const int* __restrict__ epoch_p,
                            WsLayout* __restrict__ ws, float* __restrict__ code) {
  const int t = threadIdx.x;   // 1024 threads
  __shared__ int sP[1024], sRN[1024], sU[1024];
  __shared__ float sA[1024], sPr[1024];
  int p = 0, rn = 0, u = 0;
  float a = 0.f, pr = 0.f;
  for (int j = t; j < BN; j += 1024) {
    const int l = labels[j];
    const float al = alphas[j], be = betas[j];
    const bool isp = (l == 1), isrn = (l == -1), isu = (l == 0);
    p += isp; rn += isrn; u += isu;
    a += isp ? al : 0.f;
    code[j]          = isp  ? al  : 0.f;
    code[BN + j]     = isp  ? 1.f : 0.f;
    code[2 * BN + j] = isrn ? be  : 0.f;
    code[3 * BN + j] = isu  ? 1.f : 0.f;
    const float d = pia[j] - pie[j];
    pr = fmaf(d, d, pr);
  }
  sP[t] = p; sRN[t] = rn; sU[t] = u; sA[t] = a; sPr[t] = pr;
  __syncthreads();
  for (int s = 512; s > 0; s >>= 1) {
    if (t < s) {
      sP[t] += sP[t + s]; sRN[t] += sRN[t + s]; sU[t] += sU[t + s];
      sA[t] += sA[t + s]; sPr[t] += sPr[t + s];
    }
    __syncthreads();
  }
  if (t < 64) { ws->bins_pu[t] = 0.0; ws->bins_ir[t] = 0.0; ws->bins_ic[t] = 0.0; }
  if (t == 0) {
    ws->acc_prior = (double)sPr[0];
    ws->P_tot = sP[0]; ws->RN_tot = sRN[0]; ws->U_tot = sU[0]; ws->A_tot = sA[0];
    const int ep = epoch_p[0];
    float w_inf, w_pu, w_prior;
    if (ep < 5) { w_inf = 1.f; w_pu = 0.f; w_prior = 0.f; }
    else {
      const float puw = (ep >= 15) ? 1.f : (float)(ep - 5) / 10.f;
      w_inf = 1.f - puw; w_pu = puw; w_prior = (ep >= 15) ? 1.f : 0.f;
    }
    ws->w_inf = w_inf; ws->w_pu = w_pu; ws->w_prior = w_prior;
  }
}

// ---------------- per-row PU loss + gated infonce row LSE (two-pass in registers) ----------
__launch_bounds__(NT)
__global__ void row_kernel(const float* __restrict__ sim, const float* __restrict__ pw,
                           const float* __restrict__ code, const int* __restrict__ labels,
                           const float* __restrict__ pia, WsLayout* __restrict__ ws) {
  const int row = blockIdx.x;
  const float w_pu = ws->w_pu, w_inf = ws->w_inf;
  if (w_pu == 0.0f && w_inf == 0.0f) return;
  const bool do_pu = (w_pu != 0.0f);

  const float4* __restrict__ sim4 = (const float4*)(sim + (size_t)row * BN);
  const float4* __restrict__ as4  = (const float4*)(code);
  const float4* __restrict__ ps4  = (const float4*)(code + BN);
  const float4* __restrict__ rb4  = (const float4*)(code + 2 * BN);
  const float4* __restrict__ us4  = (const float4*)(code + 3 * BN);
  // when PU is inactive, read a harmless valid buffer instead of pw (values unused)
  const float4* __restrict__ pwp  = do_pu ? (const float4*)(pw + (size_t)row * BN) : as4;

  // ---- pass A: stream sim row into registers, find block max ----
  float sv[16];
#pragma unroll
  for (int it = 0; it < 4; ++it) {
    const float4 s4 = sim4[threadIdx.x + it * NT];
    sv[4 * it + 0] = s4.x; sv[4 * it + 1] = s4.y;
    sv[4 * it + 2] = s4.z; sv[4 * it + 3] = s4.w;
  }
  float m01 = fmaxf(sv[0], sv[1]);
#pragma unroll
  for (int i = 2; i < 16; i += 2) m01 = fmaxf(m01, fmaxf(sv[i], sv[i + 1]));
  float m = m01;
#pragma unroll
  for (int off = 32; off > 0; off >>= 1) m = fmaxf(m, __shfl_xor(m, off));

  __shared__ float red[NW][8];
  const int wid = threadIdx.x >> 6;
  const int lane = threadIdx.x & 63;
  if (lane == 0) red[wid][0] = m;
  __syncthreads();
  float Msim = red[0][0];
#pragma unroll
  for (int w = 1; w < NW; ++w) Msim = fmaxf(Msim, red[w][0]);
  const float M = Msim * INV_TAU;      // row max of logits, INCLUDING self (exact; see epilogue)
  const float negM = -M;
  __syncthreads();                      // red[] reused below

  // ---- pass B: accumulate branch-free sums relative to M ----
  float se = 0.f, sp = 0.f, srn = 0.f, su = 0.f, sas = 0.f;
#pragma unroll
  for (int it = 0; it < 4; ++it) {
    const int v = threadIdx.x + it * NT;
    const float4 w4 = pwp[v];
    const float4 a4 = as4[v];
    const float4 p4 = ps4[v];
    const float4 r4 = rb4[v];
    const float4 u4 = us4[v];
    const float wv[4] = {w4.x, w4.y, w4.z, w4.w};
    const float av[4] = {a4.x, a4.y, a4.z, a4.w};
    const float pv[4] = {p4.x, p4.y, p4.z, p4.w};
    const float rv[4] = {r4.x, r4.y, r4.z, r4.w};
    const float uv[4] = {u4.x, u4.y, u4.z, u4.w};
#pragma unroll
    for (int c = 0; c < 4; ++c) {
      const float s = sv[4 * it + c];
      const float ex = __expf(fmaf(s, INV_TAU, negM));
      se += ex;
      sp = fmaf(pv[c], ex, sp);
      const float pe = wv[c] * ex;
      srn = fmaf(rv[c], pe, srn);
      su  = fmaf(uv[c], pe, su);
      sas = fmaf(av[c], s, sas);
    }
  }

#pragma unroll
  for (int off = 32; off > 0; off >>= 1) {
    se  += __shfl_xor(se, off);
    sp  += __shfl_xor(sp, off);
    srn += __shfl_xor(srn, off);
    su  += __shfl_xor(su, off);
    sas += __shfl_xor(sas, off);
  }
  if (lane == 0) {
    red[wid][0] = se; red[wid][1] = sp; red[wid][2] = srn;
    red[wid][3] = su; red[wid][4] = sas;
  }
  __syncthreads();

  if (threadIdx.x == 0) {
    double Se = 0.0, Sp = 0.0, Sr = 0.0, Su = 0.0, Sa = 0.0;
    for (int w = 0; w < NW; ++w) {
      Se += (double)red[w][0]; Sp += (double)red[w][1]; Sr += (double)red[w][2];
      Su += (double)red[w][3]; Sa += (double)red[w][4];
    }
    // diagonal contributions (self-exclusion in closed form)
    const float s_rr = sim[(size_t)row * BN + row];
    const float l_rr = s_rr * INV_TAU;
    const double ex_rr = exp((double)l_rr - (double)M);   // <= 1
    const float asr = code[row];
    const float psr = code[BN + row];
    const float rbr = code[2 * BN + row];
    const float usr = code[3 * BN + row];

    const double se_ex = fmax(Se - ex_rr, 1e-300);
    const double logZ = (double)M + log(se_ex);

    if (do_pu) {
      const float pw_rr = pw[(size_t)row * BN + row];
      const int li = labels[row];
      const int cp  = ws->P_tot  - (li == 1 ? 1 : 0);
      const int crn = ws->RN_tot - (li == -1 ? 1 : 0);
      const int cu  = ws->U_tot  - (li == 0 ? 1 : 0);
      const double Apos  = (double)ws->A_tot - (double)asr;
      const double SaL   = (double)INV_TAU * Sa - (double)asr * (double)l_rr;  // sum alpha*logit, excl self
      const double sp_ex = Sp - (double)psr * ex_rr;
      const double sr_ex = Sr - (double)rbr * (double)pw_rr * ex_rr;
      const double su_ex = Su - (double)usr * (double)pw_rr * ex_rr;

      const double Lpos = (cp > 0) ? (-(SaL - logZ * Apos) / cp) : 0.0;
      const double Lrn  = (crn > 0) ? ((sr_ex / se_ex) / crn) : 0.0;
      const double EU = (su_ex / se_ex) / (cu > 0 ? cu : 1);
      const double EP = (sp_ex / se_ex) / (cp > 0 ? cp : 1);
      double pi = (double)pia[row];
      pi = pi < 1e-4 ? 1e-4 : (pi > 0.5 ? 0.5 : pi);
      const double deb = (EU - pi * EP) / (1.0 - pi + 1e-8);
      const double Lu = (cu > 0 && cp > 0) ? (deb > 0.0 ? deb : 0.0) : 0.0;
      atomicAdd(&ws->bins_pu[row & 63], Lpos + Lrn + Lu);
    }
    if (w_inf != 0.0f) {
      const double logZf = (double)M + log(Se);   // full row LSE (self included)
      atomicAdd(&ws->bins_ir[row & 63], logZf - (double)l_rr);
    }
  }
}

// ---------------- infonce column LSE (only active when epoch < PHASE2_END) ----------------
#define COLS_PER_BLK 8
__launch_bounds__(256)
__global__ void col_kernel(const float* __restrict__ sim, WsLayout* __restrict__ ws) {
  if (ws->w_inf == 0.0f) return;
  for (int k = 0; k < COLS_PER_BLK; ++k) {
    const int col = blockIdx.x * COLS_PER_BLK + k;
    float m = -3.0e38f, se = 0.f, diag = 0.f;
    for (int r = threadIdx.x; r < BN; r += 256) {
      const float l = sim[(size_t)r * BN + col] * INV_TAU;
      if (r == col) diag = l;
      if (l > m) { se *= __expf(m - l); m = l; }
      se += __expf(l - m);
    }
#pragma unroll
    for (int off = 32; off > 0; off >>= 1) {
      const float m2 = __shfl_xor(m, off), se2 = __shfl_xor(se, off);
      diag += __shfl_xor(diag, off);
      const float mn = fmaxf(m, m2);
      se = se * __expf(m - mn) + se2 * __expf(m2 - mn);
      m = mn;
    }
    __shared__ float red[4][3];
    const int wid = threadIdx.x >> 6;
    const int lane = threadIdx.x & 63;
    if (lane == 0) { red[wid][0] = m; red[wid][1] = se; red[wid][2] = diag; }
    __syncthreads();
    if (threadIdx.x == 0) {
      float M = red[0][0], Se = red[0][1], Dg = red[0][2];
      for (int w = 1; w < 4; ++w) {
        const float mn = fmaxf(M, red[w][0]);
        Se = Se * __expf(M - mn) + red[w][1] * __expf(red[w][0] - mn);
        M = mn;
        Dg += red[w][2];
      }
      const double logZf = (double)M + log((double)Se);
      atomicAdd(&ws->bins_ic[col & 63], logZf - (double)Dg);
    }
    __syncthreads();
  }
}

// ---------------- final combine ----------------
__global__ void final_kernel(const WsLayout* __restrict__ ws, float* __restrict__ out) {
  const int t = threadIdx.x;  // 64 threads
  double pu = ws->bins_pu[t];
  double ir = ws->bins_ir[t];
  double ic = ws->bins_ic[t];
#pragma unroll
  for (int off = 32; off > 0; off >>= 1) {
    pu += __shfl_xor(pu, off);
    ir += __shfl_xor(ir, off);
    ic += __shfl_xor(ic, off);
  }
  if (t == 0) {
    const double loss_pu  = pu / (double)BN;
    const double loss_inf = (ir + ic) / (2.0 * (double)BN);
    const double prior    = ws->acc_prior / (double)BN;
    const double total = (double)ws->w_inf * loss_inf
                       + (double)ws->w_pu * loss_pu
                       + (double)ws->w_prior * 0.1 * prior;
    out[0] = (float)total;
  }
}

extern "C" void kernel_launch(void* const* d_in, const int* in_sizes, int n_in,
                              void* d_out, int out_size, void* d_ws, size_t ws_size,
                              hipStream_t stream) {
  const float* sim    = (const float*)d_in[0];
  const int*   labels = (const int*)d_in[1];
  const float* alphas = (const float*)d_in[2];
  const float* betas  = (const float*)d_in[3];
  const float* pia    = (const float*)d_in[4];
  const float* pw     = (const float*)d_in[5];
  const float* pie    = (const float*)d_in[6];
  const int*   epoch  = (const int*)d_in[7];
  WsLayout* ws = (WsLayout*)d_ws;
  float* code = (float*)((char*)d_ws + 4096);
  float* out = (float*)d_out;

  hipLaunchKernelGGL(prep_kernel, dim3(1), dim3(1024), 0, stream,
                     labels, alphas, betas, pia, pie, epoch, ws, code);
  hipLaunchKernelGGL(row_kernel, dim3(BN), dim3(NT), 0, stream,
                     sim, pw, code, labels, pia, ws);
  hipLaunchKernelGGL(col_kernel, dim3(BN / COLS_PER_BLK / 256 * 256 / 256 ? (BN / COLS_PER_BLK) : 1),
                     dim3(256), 0, stream, sim, ws);
  hipLaunchKernelGGL(final_kernel, dim3(1), dim3(64), 0, stream, ws, out);
}

// Round 3
// 119.602 us; speedup vs baseline: 1.1795x; 1.1121x over previous
//
#include <hip/hip_runtime.h>
#include <hip/hip_fp16.h>
#include <math.h>

#define BN 8192
#define NT 256
#define NW (NT / 64)
#define NGRP 8                 // groups of 4 elements per thread: 8*256*4 = 8192
#define INV_TAU (1.0f / 0.07f)
#define COFF 40.0f             // fixed softmax offset (replaces row max; exact math)

struct WsLayout {
  double bins_pu[64];   // per-row PU losses, binned
  double bins_ir[64];   // infonce row part
  double bins_ic[64];   // infonce col part
  double acc_prior;     // sum (pi_a - pi_ext)^2
  float w_inf, w_pu, w_prior;
  int P_tot, RN_tot, U_tot;
  float A_tot;          // sum of (half-rounded) alphas over label==1
};

// ---------------- prep: stats, weights, prior, packed selector code ----------------
// code[j] = half2 { value, cls } : value = alpha (pos) | beta (rn) | 0 ; cls = +1 | -1 | 0
__global__ void prep_kernel(const int* __restrict__ labels, const float* __restrict__ alphas,
                            const float* __restrict__ betas, const float* __restrict__ pia,
                            const float* __restrict__ pie, const int* __restrict__ epoch_p,
                            WsLayout* __restrict__ ws, __half2* __restrict__ code) {
  const int t = threadIdx.x;   // 1024 threads, 1 block
  __shared__ int sP[1024], sRN[1024], sU[1024];
  __shared__ float sA[1024], sPr[1024];
  int p = 0, rn = 0, u = 0;
  float a = 0.f, pr = 0.f;
  for (int j = t; j < BN; j += 1024) {
    const int l = labels[j];
    const bool isp = (l == 1), isrn = (l == -1);
    p += isp; rn += isrn; u += (l == 0);
    const __half vh = __float2half(isp ? alphas[j] : (isrn ? betas[j] : 0.f));
    const __half ch = __float2half(isp ? 1.f : (isrn ? -1.f : 0.f));
    code[j] = __halves2half2(vh, ch);
    a += isp ? __half2float(vh) : 0.f;   // A_tot from the SAME rounded alphas
    const float d = pia[j] - pie[j];
    pr = fmaf(d, d, pr);
  }
  sP[t] = p; sRN[t] = rn; sU[t] = u; sA[t] = a; sPr[t] = pr;
  __syncthreads();
  for (int s = 512; s > 0; s >>= 1) {
    if (t < s) {
      sP[t] += sP[t + s]; sRN[t] += sRN[t + s]; sU[t] += sU[t + s];
      sA[t] += sA[t + s]; sPr[t] += sPr[t + s];
    }
    __syncthreads();
  }
  if (t < 64) { ws->bins_pu[t] = 0.0; ws->bins_ir[t] = 0.0; ws->bins_ic[t] = 0.0; }
  if (t == 0) {
    ws->acc_prior = (double)sPr[0];
    ws->P_tot = sP[0]; ws->RN_tot = sRN[0]; ws->U_tot = sU[0]; ws->A_tot = sA[0];
    const int ep = epoch_p[0];
    float w_inf, w_pu, w_prior;
    if (ep < 5) { w_inf = 1.f; w_pu = 0.f; w_prior = 0.f; }
    else {
      const float puw = (ep >= 15) ? 1.f : (float)(ep - 5) / 10.f;
      w_inf = 1.f - puw; w_pu = puw; w_prior = (ep >= 15) ? 1.f : 0.f;
    }
    ws->w_inf = w_inf; ws->w_pu = w_pu; ws->w_prior = w_prior;
  }
}

// ---------------- per-row PU loss + gated infonce row LSE (single streaming pass) ----------
__launch_bounds__(NT, 4)
__global__ void row_kernel(const float* __restrict__ sim, const float* __restrict__ pw,
                           const __half2* __restrict__ code, const float* __restrict__ pia,
                           WsLayout* __restrict__ ws) {
  const int row = blockIdx.x;
  const float w_pu = ws->w_pu, w_inf = ws->w_inf;
  if (w_pu == 0.0f && w_inf == 0.0f) return;
  const bool do_pu = (w_pu != 0.0f);

  const float4* __restrict__ sim4 = (const float4*)(sim + (size_t)row * BN);
  const float4* __restrict__ cd4  = (const float4*)code;
  const float4* __restrict__ pwp  = do_pu ? (const float4*)(pw + (size_t)row * BN) : sim4;

  float se = 0.f, sp = 0.f, srn = 0.f, su = 0.f, sas = 0.f;

#pragma unroll
  for (int it = 0; it < NGRP; ++it) {
    const int v = threadIdx.x + it * NT;
    const float4 s4 = sim4[v];
    const float4 w4 = pwp[v];
    const float4 c4 = cd4[v];
    const float sv[4] = {s4.x, s4.y, s4.z, s4.w};
    const float wv[4] = {w4.x, w4.y, w4.z, w4.w};
    const float cf[4] = {c4.x, c4.y, c4.z, c4.w};
#pragma unroll
    for (int c = 0; c < 4; ++c) {
      const __half2 h = __builtin_bit_cast(__half2, cf[c]);
      const float2 f = __half22float2(h);     // f.x = value, f.y = cls (+1/-1/0)
      const float s = sv[c];
      const float ex = __expf(fmaf(s, INV_TAU, -COFF));
      se += ex;
      const bool isp  = f.y > 0.5f;
      const bool isrn = f.y < -0.5f;
      sp += isp ? ex : 0.f;
      const float we = wv[c] * ex;
      srn = fmaf(isrn ? f.x : 0.f, we, srn);
      su += (f.y == 0.f) ? we : 0.f;
      sas = fmaf(isp ? f.x : 0.f, s, sas);
    }
  }

  const int wid = threadIdx.x >> 6;
  const int lane = threadIdx.x & 63;
#pragma unroll
  for (int off = 32; off > 0; off >>= 1) {
    se  += __shfl_xor(se, off);
    sp  += __shfl_xor(sp, off);
    srn += __shfl_xor(srn, off);
    su  += __shfl_xor(su, off);
    sas += __shfl_xor(sas, off);
  }
  __shared__ float red[NW][8];
  if (lane == 0) {
    red[wid][0] = se; red[wid][1] = sp; red[wid][2] = srn;
    red[wid][3] = su; red[wid][4] = sas;
  }
  __syncthreads();

  if (threadIdx.x == 0) {
    double Se = 0.0, Sp = 0.0, Sr = 0.0, Su = 0.0, Sa = 0.0;
#pragma unroll
    for (int w = 0; w < NW; ++w) {
      Se += (double)red[w][0]; Sp += (double)red[w][1]; Sr += (double)red[w][2];
      Su += (double)red[w][3]; Sa += (double)red[w][4];
    }
    // diagonal contributions (self-exclusion in closed form); row is L2-hot
    const float s_rr = sim[(size_t)row * BN + row];
    const float l_rr = s_rr * INV_TAU;
    const float ex_rr_f = __expf(fmaf(s_rr, INV_TAU, -COFF));  // same fp as loop -> exact cancel
    const double ex_rr = (double)ex_rr_f;
    const float2 fr = __half22float2(code[row]);
    const bool rp = fr.y > 0.5f, rrn = fr.y < -0.5f, ru = (fr.y == 0.f);
    const float asr = rp ? fr.x : 0.f;
    const float rbr = rrn ? fr.x : 0.f;

    const double se_ex = fmax(Se - ex_rr, 1e-300);
    const double logZ = (double)COFF + log(se_ex);

    if (do_pu) {
      const float pw_rr = pw[(size_t)row * BN + row];
      const int cp  = ws->P_tot  - (rp ? 1 : 0);
      const int crn = ws->RN_tot - (rrn ? 1 : 0);
      const int cu  = ws->U_tot  - (ru ? 1 : 0);
      const double Apos  = (double)ws->A_tot - (double)asr;
      const double SaL   = (double)INV_TAU * Sa - (double)asr * (double)l_rr;
      const double sp_ex = Sp - (rp ? ex_rr : 0.0);
      const double sr_ex = Sr - (double)rbr * (double)pw_rr * ex_rr;
      const double su_ex = Su - (ru ? (double)pw_rr * ex_rr : 0.0);

      const double Lpos = (cp > 0) ? (-(SaL - logZ * Apos) / cp) : 0.0;
      const double Lrn  = (crn > 0) ? ((sr_ex / se_ex) / crn) : 0.0;
      const double EU = (su_ex / se_ex) / (cu > 0 ? cu : 1);
      const double EP = (sp_ex / se_ex) / (cp > 0 ? cp : 1);
      double pi = (double)pia[row];
      pi = pi < 1e-4 ? 1e-4 : (pi > 0.5 ? 0.5 : pi);
      const double deb = (EU - pi * EP) / (1.0 - pi + 1e-8);
      const double Lu = (cu > 0 && cp > 0) ? (deb > 0.0 ? deb : 0.0) : 0.0;
      atomicAdd(&ws->bins_pu[row & 63], Lpos + Lrn + Lu);
    }
    if (w_inf != 0.0f) {
      const double logZf = (double)COFF + log(Se);   // full row LSE (self included)
      atomicAdd(&ws->bins_ir[row & 63], logZf - (double)l_rr);
    }
  }
}

// ---------------- infonce column LSE (only active when epoch < PHASE2_END) ----------------
#define COLS_PER_BLK 8
__launch_bounds__(256)
__global__ void col_kernel(const float* __restrict__ sim, WsLayout* __restrict__ ws) {
  if (ws->w_inf == 0.0f) return;
  for (int k = 0; k < COLS_PER_BLK; ++k) {
    const int col = blockIdx.x * COLS_PER_BLK + k;
    float m = -3.0e38f, se = 0.f, diag = 0.f;
    for (int r = threadIdx.x; r < BN; r += 256) {
      const float l = sim[(size_t)r * BN + col] * INV_TAU;
      if (r == col) diag = l;
      if (l > m) { se *= __expf(m - l); m = l; }
      se += __expf(l - m);
    }
#pragma unroll
    for (int off = 32; off > 0; off >>= 1) {
      const float m2 = __shfl_xor(m, off), se2 = __shfl_xor(se, off);
      diag += __shfl_xor(diag, off);
      const float mn = fmaxf(m, m2);
      se = se * __expf(m - mn) + se2 * __expf(m2 - mn);
      m = mn;
    }
    __shared__ float red[4][3];
    const int wid = threadIdx.x >> 6;
    const int lane = threadIdx.x & 63;
    if (lane == 0) { red[wid][0] = m; red[wid][1] = se; red[wid][2] = diag; }
    __syncthreads();
    if (threadIdx.x == 0) {
      float M = red[0][0], Se = red[0][1], Dg = red[0][2];
      for (int w = 1; w < 4; ++w) {
        const float mn = fmaxf(M, red[w][0]);
        Se = Se * __expf(M - mn) + red[w][1] * __expf(red[w][0] - mn);
        M = mn;
        Dg += red[w][2];
      }
      const double logZf = (double)M + log((double)Se);
      atomicAdd(&ws->bins_ic[col & 63], logZf - (double)Dg);
    }
    __syncthreads();
  }
}

// ---------------- final combine ----------------
__global__ void final_kernel(const WsLayout* __restrict__ ws, float* __restrict__ out) {
  const int t = threadIdx.x;  // 64 threads
  double pu = ws->bins_pu[t];
  double ir = ws->bins_ir[t];
  double ic = ws->bins_ic[t];
#pragma unroll
  for (int off = 32; off > 0; off >>= 1) {
    pu += __shfl_xor(pu, off);
    ir += __shfl_xor(ir, off);
    ic += __shfl_xor(ic, off);
  }
  if (t == 0) {
    const double loss_pu  = pu / (double)BN;
    const double loss_inf = (ir + ic) / (2.0 * (double)BN);
    const double prior    = ws->acc_prior / (double)BN;
    const double total = (double)ws->w_inf * loss_inf
                       + (double)ws->w_pu * loss_pu
                       + (double)ws->w_prior * 0.1 * prior;
    out[0] = (float)total;
  }
}

extern "C" void kernel_launch(void* const* d_in, const int* in_sizes, int n_in,
                              void* d_out, int out_size, void* d_ws, size_t ws_size,
                              hipStream_t stream) {
  const float* sim    = (const float*)d_in[0];
  const int*   labels = (const int*)d_in[1];
  const float* alphas = (const float*)d_in[2];
  const float* betas  = (const float*)d_in[3];
  const float* pia    = (const float*)d_in[4];
  const float* pw     = (const float*)d_in[5];
  const float* pie    = (const float*)d_in[6];
  const int*   epoch  = (const int*)d_in[7];
  WsLayout* ws = (WsLayout*)d_ws;
  __half2* code = (__half2*)((char*)d_ws + 4096);
  float* out = (float*)d_out;

  hipLaunchKernelGGL(prep_kernel, dim3(1), dim3(1024), 0, stream,
                     labels, alphas, betas, pia, pie, epoch, ws, code);
  hipLaunchKernelGGL(row_kernel, dim3(BN), dim3(NT), 0, stream,
                     sim, pw, code, pia, ws);
  hipLaunchKernelGGL(col_kernel, dim3(BN / COLS_PER_BLK), dim3(256), 0, stream, sim, ws);
  hipLaunchKernelGGL(final_kernel, dim3(1), dim3(64), 0, stream, ws, out);
}

// Round 4
// 113.808 us; speedup vs baseline: 1.2395x; 1.0509x over previous
//
#include <hip/hip_runtime.h>
#include <hip/hip_fp16.h>
#include <math.h>

#define BN 8192
#define NT 512
#define NW (NT / 64)
#define NGRP 4                 // 4 float4-groups/thread: 4*512*4 = 8192
#define INV_TAU (1.0f / 0.07f)
#define COFF 40.0f             // fixed softmax offset (replaces row max; exact math)

struct WsLayout {
  double bins_pu[64];   // per-row PU losses, binned
  double bins_ir[64];   // infonce row part
  double bins_ic[64];   // infonce col part
  double acc_prior;     // sum (pi_a - pi_ext)^2
  float w_inf, w_pu, w_prior;
  int P_tot, RN_tot, U_tot;
  float A_tot;          // sum of (half-rounded) alphas over label==1
};

// ---------------- prep: stats, weights, prior, packed selector code ----------------
// code[j] = half2 { value, cls } : value = alpha (pos) | beta (rn) | 0 ; cls = +1 | -1 | 0
__global__ void prep_kernel(const int* __restrict__ labels, const float* __restrict__ alphas,
                            const float* __restrict__ betas, const float* __restrict__ pia,
                            const float* __restrict__ pie, const int* __restrict__ epoch_p,
                            WsLayout* __restrict__ ws, __half2* __restrict__ code) {
  const int t = threadIdx.x;   // 1024 threads, 1 block
  __shared__ int sP[1024], sRN[1024];
  __shared__ float sA[1024], sPr[1024];
  int p = 0, rn = 0;
  float a = 0.f, pr = 0.f;
  const int4*   lb4 = (const int4*)labels;
  const float4* al4 = (const float4*)alphas;
  const float4* be4 = (const float4*)betas;
  const float4* pa4 = (const float4*)pia;
  const float4* pe4 = (const float4*)pie;
#pragma unroll
  for (int g = 0; g < BN / 4 / 1024; ++g) {
    const int v = t + g * 1024;
    const int4 l4 = lb4[v];
    const float4 a4 = al4[v];
    const float4 b4 = be4[v];
    const float4 x4 = pa4[v];
    const float4 e4 = pe4[v];
    const int lv[4] = {l4.x, l4.y, l4.z, l4.w};
    const float av[4] = {a4.x, a4.y, a4.z, a4.w};
    const float bv[4] = {b4.x, b4.y, b4.z, b4.w};
    const float xv[4] = {x4.x, x4.y, x4.z, x4.w};
    const float ev[4] = {e4.x, e4.y, e4.z, e4.w};
#pragma unroll
    for (int c = 0; c < 4; ++c) {
      const int l = lv[c];
      const bool isp = (l == 1), isrn = (l == -1);
      p += isp; rn += isrn;
      const __half vh = __float2half(isp ? av[c] : (isrn ? bv[c] : 0.f));
      const __half ch = __float2half(isp ? 1.f : (isrn ? -1.f : 0.f));
      code[4 * v + c] = __halves2half2(vh, ch);
      a += isp ? __half2float(vh) : 0.f;
      const float d = xv[c] - ev[c];
      pr = fmaf(d, d, pr);
    }
  }
  sP[t] = p; sRN[t] = rn; sA[t] = a; sPr[t] = pr;
  __syncthreads();
  for (int s = 512; s > 0; s >>= 1) {
    if (t < s) {
      sP[t] += sP[t + s]; sRN[t] += sRN[t + s];
      sA[t] += sA[t + s]; sPr[t] += sPr[t + s];
    }
    __syncthreads();
  }
  if (t < 64) { ws->bins_pu[t] = 0.0; ws->bins_ir[t] = 0.0; ws->bins_ic[t] = 0.0; }
  if (t == 0) {
    ws->acc_prior = (double)sPr[0];
    ws->P_tot = sP[0]; ws->RN_tot = sRN[0];
    ws->U_tot = BN - sP[0] - sRN[0];
    ws->A_tot = sA[0];
    const int ep = epoch_p[0];
    float w_inf, w_pu, w_prior;
    if (ep < 5) { w_inf = 1.f; w_pu = 0.f; w_prior = 0.f; }
    else {
      const float puw = (ep >= 15) ? 1.f : (float)(ep - 5) / 10.f;
      w_inf = 1.f - puw; w_pu = puw; w_prior = (ep >= 15) ? 1.f : 0.f;
    }
    ws->w_inf = w_inf; ws->w_pu = w_pu; ws->w_prior = w_prior;
  }
}

// ---------------- per-row PU loss + gated infonce row LSE ----------------
// All 12 float4 loads hoisted into registers before compute (deep MLP).
__launch_bounds__(NT, 4)
__global__ void row_kernel(const float* __restrict__ sim, const float* __restrict__ pw,
                           const __half2* __restrict__ code, const float* __restrict__ pia,
                           WsLayout* __restrict__ ws) {
  const int row = blockIdx.x;
  const float w_pu = ws->w_pu, w_inf = ws->w_inf;
  if (w_pu == 0.0f && w_inf == 0.0f) return;
  const bool do_pu = (w_pu != 0.0f);

  const float4* __restrict__ sim4 = (const float4*)(sim + (size_t)row * BN);
  const float4* __restrict__ cd4  = (const float4*)code;
  const float4* __restrict__ pwp  = do_pu ? (const float4*)(pw + (size_t)row * BN) : sim4;

  // ---- hoisted loads: 12 outstanding float4 per thread ----
  float4 s4[NGRP], w4[NGRP], c4[NGRP];
#pragma unroll
  for (int it = 0; it < NGRP; ++it) s4[it] = sim4[threadIdx.x + it * NT];
#pragma unroll
  for (int it = 0; it < NGRP; ++it) w4[it] = pwp[threadIdx.x + it * NT];
#pragma unroll
  for (int it = 0; it < NGRP; ++it) c4[it] = cd4[threadIdx.x + it * NT];

  float se = 0.f, sp = 0.f, srn = 0.f, su = 0.f, sas = 0.f;
#pragma unroll
  for (int it = 0; it < NGRP; ++it) {
    const float sv[4] = {s4[it].x, s4[it].y, s4[it].z, s4[it].w};
    const float wv[4] = {w4[it].x, w4[it].y, w4[it].z, w4[it].w};
    const float cf[4] = {c4[it].x, c4[it].y, c4[it].z, c4[it].w};
#pragma unroll
    for (int c = 0; c < 4; ++c) {
      const __half2 h = __builtin_bit_cast(__half2, cf[c]);
      const float2 f = __half22float2(h);     // f.x = value, f.y = cls (+1/-1/0)
      const float s = sv[c];
      const float ex = __expf(fmaf(s, INV_TAU, -COFF));
      se += ex;
      const bool isp  = f.y > 0.5f;
      const bool isrn = f.y < -0.5f;
      sp += isp ? ex : 0.f;
      const float we = wv[c] * ex;
      srn = fmaf(isrn ? f.x : 0.f, we, srn);
      su += (f.y == 0.f) ? we : 0.f;
      sas = fmaf(isp ? f.x : 0.f, s, sas);
    }
  }

  const int wid = threadIdx.x >> 6;
  const int lane = threadIdx.x & 63;
#pragma unroll
  for (int off = 32; off > 0; off >>= 1) {
    se  += __shfl_xor(se, off);
    sp  += __shfl_xor(sp, off);
    srn += __shfl_xor(srn, off);
    su  += __shfl_xor(su, off);
    sas += __shfl_xor(sas, off);
  }
  __shared__ float red[NW][8];
  if (lane == 0) {
    red[wid][0] = se; red[wid][1] = sp; red[wid][2] = srn;
    red[wid][3] = su; red[wid][4] = sas;
  }
  __syncthreads();

  if (threadIdx.x == 0) {
    double Se = 0.0, Sp = 0.0, Sr = 0.0, Su = 0.0, Sa = 0.0;
#pragma unroll
    for (int w = 0; w < NW; ++w) {
      Se += (double)red[w][0]; Sp += (double)red[w][1]; Sr += (double)red[w][2];
      Su += (double)red[w][3]; Sa += (double)red[w][4];
    }
    // diagonal contributions (self-exclusion in closed form); row is cache-hot
    const float s_rr = sim[(size_t)row * BN + row];
    const float l_rr = s_rr * INV_TAU;
    const float ex_rr_f = __expf(fmaf(s_rr, INV_TAU, -COFF));  // same fp as loop -> exact cancel
    const double ex_rr = (double)ex_rr_f;
    const float2 fr = __half22float2(code[row]);
    const bool rp = fr.y > 0.5f, rrn = fr.y < -0.5f, ru = (fr.y == 0.f);
    const float asr = rp ? fr.x : 0.f;
    const float rbr = rrn ? fr.x : 0.f;

    const double se_ex = fmax(Se - ex_rr, 1e-300);
    const double logZ = (double)COFF + log(se_ex);

    if (do_pu) {
      const float pw_rr = pw[(size_t)row * BN + row];
      const int cp  = ws->P_tot  - (rp ? 1 : 0);
      const int crn = ws->RN_tot - (rrn ? 1 : 0);
      const int cu  = ws->U_tot  - (ru ? 1 : 0);
      const double Apos  = (double)ws->A_tot - (double)asr;
      const double SaL   = (double)INV_TAU * Sa - (double)asr * (double)l_rr;
      const double sp_ex = Sp - (rp ? ex_rr : 0.0);
      const double sr_ex = Sr - (double)rbr * (double)pw_rr * ex_rr;
      const double su_ex = Su - (ru ? (double)pw_rr * ex_rr : 0.0);

      const double Lpos = (cp > 0) ? (-(SaL - logZ * Apos) / cp) : 0.0;
      const double Lrn  = (crn > 0) ? ((sr_ex / se_ex) / crn) : 0.0;
      const double EU = (su_ex / se_ex) / (cu > 0 ? cu : 1);
      const double EP = (sp_ex / se_ex) / (cp > 0 ? cp : 1);
      double pi = (double)pia[row];
      pi = pi < 1e-4 ? 1e-4 : (pi > 0.5 ? 0.5 : pi);
      const double deb = (EU - pi * EP) / (1.0 - pi + 1e-8);
      const double Lu = (cu > 0 && cp > 0) ? (deb > 0.0 ? deb : 0.0) : 0.0;
      atomicAdd(&ws->bins_pu[row & 63], Lpos + Lrn + Lu);
    }
    if (w_inf != 0.0f) {
      const double logZf = (double)COFF + log(Se);   // full row LSE (self included)
      atomicAdd(&ws->bins_ir[row & 63], logZf - (double)l_rr);
    }
  }
}

// ---------------- infonce column LSE (only active when epoch < PHASE2_END) ----------------
#define COL_BLKS 256
#define COLS_PER_BLK (BN / COL_BLKS)
__launch_bounds__(256)
__global__ void col_kernel(const float* __restrict__ sim, WsLayout* __restrict__ ws) {
  if (ws->w_inf == 0.0f) return;
  for (int k = 0; k < COLS_PER_BLK; ++k) {
    const int col = blockIdx.x * COLS_PER_BLK + k;
    float m = -3.0e38f, se = 0.f, diag = 0.f;
    for (int r = threadIdx.x; r < BN; r += 256) {
      const float l = sim[(size_t)r * BN + col] * INV_TAU;
      if (r == col) diag = l;
      if (l > m) { se *= __expf(m - l); m = l; }
      se += __expf(l - m);
    }
#pragma unroll
    for (int off = 32; off > 0; off >>= 1) {
      const float m2 = __shfl_xor(m, off), se2 = __shfl_xor(se, off);
      diag += __shfl_xor(diag, off);
      const float mn = fmaxf(m, m2);
      se = se * __expf(m - mn) + se2 * __expf(m2 - mn);
      m = mn;
    }
    __shared__ float red[4][3];
    const int wid = threadIdx.x >> 6;
    const int lane = threadIdx.x & 63;
    if (lane == 0) { red[wid][0] = m; red[wid][1] = se; red[wid][2] = diag; }
    __syncthreads();
    if (threadIdx.x == 0) {
      float M = red[0][0], Se = red[0][1], Dg = red[0][2];
      for (int w = 1; w < 4; ++w) {
        const float mn = fmaxf(M, red[w][0]);
        Se = Se * __expf(M - mn) + red[w][1] * __expf(red[w][0] - mn);
        M = mn;
        Dg += red[w][2];
      }
      const double logZf = (double)M + log((double)Se);
      atomicAdd(&ws->bins_ic[col & 63], logZf - (double)Dg);
    }
    __syncthreads();
  }
}

// ---------------- final combine ----------------
__global__ void final_kernel(const WsLayout* __restrict__ ws, float* __restrict__ out) {
  const int t = threadIdx.x;  // 64 threads
  double pu = ws->bins_pu[t];
  double ir = ws->bins_ir[t];
  double ic = ws->bins_ic[t];
#pragma unroll
  for (int off = 32; off > 0; off >>= 1) {
    pu += __shfl_xor(pu, off);
    ir += __shfl_xor(ir, off);
    ic += __shfl_xor(ic, off);
  }
  if (t == 0) {
    const double loss_pu  = pu / (double)BN;
    const double loss_inf = (ir + ic) / (2.0 * (double)BN);
    const double prior    = ws->acc_prior / (double)BN;
    const double total = (double)ws->w_inf * loss_inf
                       + (double)ws->w_pu * loss_pu
                       + (double)ws->w_prior * 0.1 * prior;
    out[0] = (float)total;
  }
}

extern "C" void kernel_launch(void* const* d_in, const int* in_sizes, int n_in,
                              void* d_out, int out_size, void* d_ws, size_t ws_size,
                              hipStream_t stream) {
  const float* sim    = (const float*)d_in[0];
  const int*   labels = (const int*)d_in[1];
  const float* alphas = (const float*)d_in[2];
  const float* betas  = (const float*)d_in[3];
  const float* pia    = (const float*)d_in[4];
  const float* pw     = (const float*)d_in[5];
  const float* pie    = (const float*)d_in[6];
  const int*   epoch  = (const int*)d_in[7];
  WsLayout* ws = (WsLayout*)d_ws;
  __half2* code = (__half2*)((char*)d_ws + 4096);
  float* out = (float*)d_out;

  hipLaunchKernelGGL(prep_kernel, dim3(1), dim3(1024), 0, stream,
                     labels, alphas, betas, pia, pie, epoch, ws, code);
  hipLaunchKernelGGL(row_kernel, dim3(BN), dim3(NT), 0, stream,
                     sim, pw, code, pia, ws);
  hipLaunchKernelGGL(col_kernel, dim3(COL_BLKS), dim3(256), 0, stream, sim, ws);
  hipLaunchKernelGGL(final_kernel, dim3(1), dim3(64), 0, stream, ws, out);
}